// Round 6
// baseline (1393.049 us; speedup 1.0000x reference)
//
#include <hip/hip_runtime.h>
#include <hip/hip_cooperative_groups.h>

namespace cg = cooperative_groups;

// AttentionBasedNN: 4-layer additive attention + residual FCs + head.
// VEC=1280, HID=128, B=4, S=256. fp32 (no fp32 MFMA on CDNA4 -> vector ALU).
//
// Round-6: persistent cooperative kernel, grid = 256 blocks (1 block/CU --
// cannot be occupancy-rejected), vblock loops are grid-size agnostic.
// Added the __syncthreads() guarding the LDS union when a block runs a
// GEMM vblock followed by the q4-GEMV vblock in the same phase.

#define DEV __device__ __forceinline__

static constexpr int VEC = 1280;
static constexpr int HID = 128;
static constexpr int BB  = 4;
static constexpr int SS  = 256;
static constexpr int MROWS = BB * SS;   // 1024
static constexpr int NPART = 8;         // split-K partials (QK and FC1)

DEV float ftanh(float x) {
  float e = __expf(2.0f * x);
  return 1.0f - __fdividef(2.0f, e + 1.0f);
}

DEV float waveSum(float v) {
#pragma unroll
  for (int off = 32; off > 0; off >>= 1) v += __shfl_xor(v, off, 64);
  return v;
}
DEV float waveMax(float v) {
#pragma unroll
  for (int off = 32; off > 0; off >>= 1) v = fmaxf(v, __shfl_xor(v, off, 64));
  return v;
}
DEV float blockSum(float v, float* red) {
  v = waveSum(v);
  int tid = threadIdx.x;
  if ((tid & 63) == 0) red[tid >> 6] = v;
  __syncthreads();
  float r = (red[0] + red[1]) + (red[2] + red[3]);
  __syncthreads();
  return r;
}
DEV float blockMax(float v, float* red) {
  v = waveMax(v);
  int tid = threadIdx.x;
  if ((tid & 63) == 0) red[tid >> 6] = v;
  __syncthreads();
  float r = fmaxf(fmaxf(red[0], red[1]), fmaxf(red[2], red[3]));
  __syncthreads();
  return r;
}

struct SmemGemm { float As[16][68]; float Bs[16][68]; };
union Smem {
  SmemGemm g;
  struct { float qs[2][128]; float wvs[128]; } s;
  struct { float xrow[1280]; float partial[256]; float h1s[32]; float h2s[12]; } t;
  float aws[256];
};

// 64x64 tile fp32 GEMM phase body, BK=16, 4x4 microtile, reg double-buffer.
// Safe for back-to-back calls: first action in the k-loop is __syncthreads()
// BEFORE any LDS write, protecting the previous call's readers.
// AFUSE: A = relu(sum of NP partials (stride aPart) + aBias[k]).
template <int NP, bool AFUSE, bool OBIAS, bool ORES>
DEV void gemm_tile(SmemGemm& smg,
                   const float* __restrict__ A, int ldA, long aPart,
                   const float* __restrict__ B, int ldB, int nb,
                   float* __restrict__ C, int ldC,
                   int m0, int n0, int kBeg, int kEnd,
                   const float* __restrict__ aBias,
                   const float* __restrict__ oBias,
                   const float* __restrict__ res) {
  const int tid = threadIdx.x;
  const int tx = tid & 15, ty = tid >> 4;
  const int ar = tid >> 2, ac = (tid & 3) << 2;   // A: row 0..63, k {0,4,8,12}
  const int br = tid >> 4, bc = (tid & 15) << 2;  // B: k-row 0..15, col 0..60

  auto loadA = [&](int kt) -> float4 {
    const size_t off = (size_t)(m0 + ar) * ldA + kt + ac;
    float4 s = *(const float4*)(A + off);
    if (AFUSE) {
#pragma unroll
      for (int p2 = 1; p2 < NP; ++p2) {
        const float4 t2 = *(const float4*)(A + (long)p2 * aPart + off);
        s.x += t2.x; s.y += t2.y; s.z += t2.z; s.w += t2.w;
      }
      const float4 bz = *(const float4*)(aBias + kt + ac);
      s.x = fmaxf(s.x + bz.x, 0.0f);
      s.y = fmaxf(s.y + bz.y, 0.0f);
      s.z = fmaxf(s.z + bz.z, 0.0f);
      s.w = fmaxf(s.w + bz.w, 0.0f);
    }
    return s;
  };
  auto loadB = [&](int kt) -> float4 {
    return *(const float4*)(B + (size_t)(kt + br) * ldB + nb + bc);
  };

  float acc[4][4] = {};
  float4 a4 = loadA(kBeg);
  float4 b4 = loadB(kBeg);

  for (int kt = kBeg; kt < kEnd; kt += 16) {
    __syncthreads();
    smg.As[ac + 0][ar] = a4.x;
    smg.As[ac + 1][ar] = a4.y;
    smg.As[ac + 2][ar] = a4.z;
    smg.As[ac + 3][ar] = a4.w;
    *(float4*)&smg.Bs[br][bc] = b4;
    __syncthreads();
    if (kt + 16 < kEnd) {  // prefetch next tile under compute
      a4 = loadA(kt + 16);
      b4 = loadB(kt + 16);
    }
#pragma unroll
    for (int kk = 0; kk < 16; ++kk) {
      const float4 av = *(const float4*)&smg.As[kk][ty << 2];
      const float4 bv = *(const float4*)&smg.Bs[kk][tx << 2];
      const float a[4] = {av.x, av.y, av.z, av.w};
      const float b[4] = {bv.x, bv.y, bv.z, bv.w};
#pragma unroll
      for (int i = 0; i < 4; ++i)
#pragma unroll
        for (int j = 0; j < 4; ++j) acc[i][j] = fmaf(a[i], b[j], acc[i][j]);
    }
  }

#pragma unroll
  for (int i = 0; i < 4; ++i) {
    const int m = m0 + (ty << 2) + i;
#pragma unroll
    for (int j = 0; j < 4; ++j) {
      const int n = n0 + (tx << 2) + j;
      float v = acc[i][j];
      if (OBIAS) v += oBias[n];
      if (ORES) v += res[(size_t)m * ldC + n];
      C[(size_t)m * ldC + n] = v;
    }
  }
}

struct Params {
  const float* X; const int* lys;
  const float* Wq[4]; const float* Wk[4]; const float* wv[4];
  const float* rW1[3]; const float* rb1[3];
  const float* rW2[3]; const float* rb2[3];
  const float* hW1; const float* hb1;
  const float* hW2; const float* hb2;
  const float* hW3; const float* hb3;
  float* out;
  float* QKp; float* Qd; float* KT; float* attn;
  float* Yraw; float* Yb; float* Hp;
  float* buf0; float* buf1;
  float* q4d; float* aw4; float* A4;
};

static constexpr long QK_PS = 262144;  // QK partial stride (1024*256)
static constexpr long H_PS  = 131072;  // FC1/K4 partial stride (1024*128)

__global__ __launch_bounds__(256, 1) void net_k(Params p) {
  cg::grid_group grid = cg::this_grid();
  __shared__ Smem sm;
  __shared__ float red[4];
  const int blk = blockIdx.x, G = gridDim.x, tid = threadIdx.x;

  const float* Pin[3] = {p.X, p.buf0, p.buf1};
  float* Pout[3] = {p.buf0, p.buf1, p.buf0};

  for (int l = 0; l < 3; ++l) {
    const float* Xin = Pin[l];

    // ---- QK: QKp[z] = Xin @ [Wq|Wk], split-K=8. 512 vblocks. ----
    for (int vb = blk; vb < 512; vb += G) {
      const int x = vb & 3, y = (vb >> 2) & 15, z = vb >> 6;
      const int n0 = x * 64;
      const float* Bsel = (n0 < HID) ? p.Wq[l] : p.Wk[l];
      const int nb = (n0 < HID) ? n0 : n0 - HID;
      gemm_tile<1, false, false, false>(
          sm.g, Xin, VEC, 0, Bsel, HID, nb, p.QKp + (long)z * QK_PS, 256,
          y * 64, n0, z * 160, z * 160 + 160, nullptr, nullptr, nullptr);
    }
    grid.sync();

    // ---- qksum: reduce partials -> Qd dense + KT transposed. no LDS. ----
    for (int vb = blk; vb < MROWS; vb += G) {
      const int b = vb >> 8, j = vb & 255;
      const size_t off = (size_t)vb * 256 + tid;
      float v = 0.0f;
#pragma unroll
      for (int q = 0; q < NPART; ++q) v += p.QKp[(long)q * QK_PS + off];
      if (tid < 128) p.Qd[(size_t)vb * 128 + tid] = v;
      else p.KT[(size_t)b * 32768 + (size_t)(tid - 128) * 256 + j] = v;
    }
    grid.sync();

    // ---- scores + softmax: 512 vblocks (2 q-rows each), KT coalesced.
    // LDS-safe across iterations: final blockSum's trailing barrier covers
    // all qs/wvs reads before the next iteration's writes. ----
    for (int vb = blk; vb < 512; vb += G) {
      const int b = vb >> 7, i0 = (vb & 127) * 2;
      {
        const int rr = tid >> 7, h = tid & 127;
        sm.s.qs[rr][h] = p.Qd[(size_t)(b * 256 + i0 + rr) * 128 + h];
      }
      if (tid < 128) sm.s.wvs[tid] = p.wv[l][tid];
      __syncthreads();
      const float* KTb = p.KT + (size_t)b * 32768 + tid;
      float s0 = 0.0f, s1 = 0.0f;
#pragma unroll 4
      for (int h = 0; h < 128; h += 4) {
        const float k0 = KTb[(h + 0) * 256];
        const float k1 = KTb[(h + 1) * 256];
        const float k2 = KTb[(h + 2) * 256];
        const float k3 = KTb[(h + 3) * 256];
        const float w0 = sm.s.wvs[h], w1 = sm.s.wvs[h + 1];
        const float w2 = sm.s.wvs[h + 2], w3 = sm.s.wvs[h + 3];
        s0 += w0 * ftanh(sm.s.qs[0][h] + k0) + w1 * ftanh(sm.s.qs[0][h + 1] + k1) +
              w2 * ftanh(sm.s.qs[0][h + 2] + k2) + w3 * ftanh(sm.s.qs[0][h + 3] + k3);
        s1 += w0 * ftanh(sm.s.qs[1][h] + k0) + w1 * ftanh(sm.s.qs[1][h + 1] + k1) +
              w2 * ftanh(sm.s.qs[1][h + 2] + k2) + w3 * ftanh(sm.s.qs[1][h + 3] + k3);
      }
      {
        const float mx = blockMax(s0, red);
        const float e = __expf(s0 - mx);
        const float tot = blockSum(e, red);
        p.attn[(size_t)(b * 256 + i0) * 256 + tid] = e / tot;
      }
      {
        const float mx = blockMax(s1, red);
        const float e = __expf(s1 - mx);
        const float tot = blockSum(e, red);
        p.attn[(size_t)(b * 256 + i0 + 1) * 256 + tid] = e / tot;
      }
    }
    grid.sync();

    // ---- PV: Yraw = attn @ Xin + Xin (batched, residual fused). 320 vb. ----
    for (int vb = blk; vb < 320; vb += G) {
      const int x = vb % 20, rest = vb / 20;
      const int y = rest & 3, b = rest >> 2;
      gemm_tile<1, false, false, true>(
          sm.g, p.attn + (long)b * SS * SS, 256, 0,
          Xin + (long)b * SS * VEC, VEC, x * 64,
          p.Yraw + (long)b * SS * VEC, VEC,
          y * 64, x * 64, 0, 256, nullptr, nullptr, Xin + (long)b * SS * VEC);
    }
    grid.sync();

    // ---- LN: Yb = LN(Yraw). no LDS except red (barrier-guarded). ----
    for (int vb = blk; vb < MROWS; vb += G) {
      const float* a = p.Yraw + (size_t)vb * VEC;
      float v[5];
      float sum = 0.0f;
#pragma unroll
      for (int k = 0; k < 5; ++k) {
        v[k] = a[tid + k * 256];
        sum += v[k];
      }
      sum = blockSum(sum, red);
      const float m = sum * (1.0f / VEC);
      float sq = 0.0f;
#pragma unroll
      for (int k = 0; k < 5; ++k) {
        const float dl = v[k] - m;
        sq += dl * dl;
      }
      sq = blockSum(sq, red);
      const float rstd = rsqrtf(sq * (1.0f / VEC) + 1e-5f);
      float* y = p.Yb + (size_t)vb * VEC;
#pragma unroll
      for (int k = 0; k < 5; ++k) y[tid + k * 256] = (v[k] - m) * rstd;
    }
    grid.sync();

    // ---- FC1: Hp[z] = Yb @ rW1, split-K=8. 256 vblocks. ----
    for (int vb = blk; vb < 256; vb += G) {
      const int x = vb & 1, y = (vb >> 1) & 15, z = vb >> 5;
      gemm_tile<1, false, false, false>(
          sm.g, p.Yb, VEC, 0, p.rW1[l], HID, x * 64,
          p.Hp + (long)z * H_PS, HID,
          y * 64, x * 64, z * 160, z * 160 + 160, nullptr, nullptr, nullptr);
    }
    grid.sync();

    // ---- FC2: Xout = relu(sum(Hp)+b1) @ rW2 + b2 + Yb. 320 vblocks. ----
    for (int vb = blk; vb < 320; vb += G) {
      const int x = vb % 20, y = vb / 20;
      gemm_tile<NPART, true, true, true>(
          sm.g, p.Hp, HID, H_PS, p.rW2[l], VEC, x * 64,
          Pout[l], VEC,
          y * 64, x * 64, 0, HID, p.rb1[l], p.rb2[l], p.Yb);
    }
    grid.sync();
  }

  const float* X3 = p.buf0;
  const int lp = p.lys[0];

  // ---- K4: K-proj split-K=8 (vb 0..255) + q4 GEMV (vb 256..259). ----
  for (int vb = blk; vb < 260; vb += G) {
    if (vb < 256) {
      const int x = vb & 1, y = (vb >> 1) & 15, z = vb >> 5;
      gemm_tile<1, false, false, false>(
          sm.g, X3, VEC, 0, p.Wk[3], HID, x * 64,
          p.QKp + (long)z * H_PS, HID,
          y * 64, x * 64, z * 160, z * 160 + 160, nullptr, nullptr, nullptr);
    } else {
      __syncthreads();  // LDS union: prior gemm_tile readers must finish
      const int b = vb - 256;
      const float* xr = X3 + (size_t)(b * 256 + lp) * VEC;
      const int h = tid & 127, half = tid >> 7;
      float acc = 0.0f;
      const int k0 = half * 640;
      for (int k = k0; k < k0 + 640; ++k)
        acc = fmaf(xr[k], p.Wq[3][(size_t)k * HID + h], acc);
      sm.t.partial[tid] = acc;
      __syncthreads();
      if (tid < 128)
        p.q4d[b * 128 + tid] = sm.t.partial[tid] + sm.t.partial[tid + 128];
      __syncthreads();
    }
  }
  grid.sync();

  // ---- kt4sum: sum K4 partials -> KT. no LDS. ----
  for (int vb = blk; vb < 512; vb += G) {
    const int r = vb * 2 + (tid >> 7), h = tid & 127;
    const int b = r >> 8, j = r & 255;
    const size_t off = (size_t)r * 128 + h;
    float v = 0.0f;
#pragma unroll
    for (int q = 0; q < NPART; ++q) v += p.QKp[(long)q * H_PS + off];
    p.KT[(size_t)b * 32768 + (size_t)h * 256 + j] = v;
  }
  grid.sync();

  // ---- scores4: 4 vblocks (one iteration per block). ----
  for (int vb = blk; vb < BB; vb += G) {
    const int b = vb;
    if (tid < 128) {
      sm.s.qs[0][tid] = p.q4d[b * 128 + tid];
      sm.s.wvs[tid] = p.wv[3][tid];
    }
    __syncthreads();
    const float* KTb = p.KT + (size_t)b * 32768 + tid;
    float s = 0.0f;
#pragma unroll 4
    for (int h = 0; h < 128; h += 4) {
      s += sm.s.wvs[h + 0] * ftanh(sm.s.qs[0][h + 0] + KTb[(h + 0) * 256]);
      s += sm.s.wvs[h + 1] * ftanh(sm.s.qs[0][h + 1] + KTb[(h + 1) * 256]);
      s += sm.s.wvs[h + 2] * ftanh(sm.s.qs[0][h + 2] + KTb[(h + 2) * 256]);
      s += sm.s.wvs[h + 3] * ftanh(sm.s.qs[0][h + 3] + KTb[(h + 3) * 256]);
    }
    const float mx = blockMax(s, red);
    const float e = __expf(s - mx);
    const float tot = blockSum(e, red);
    p.aw4[b * 256 + tid] = e / tot;
  }
  grid.sync();

  // ---- pv4: A4[b][c] = sum_j aw4[b][j]*X3[b,j,c] + X3[b,lp,c]. 20 vb. ----
  for (int vb = blk; vb < 20; vb += G) {
    const int b = vb & 3, cs = vb >> 2;
    const int c = cs * 256 + tid;
    sm.aws[tid] = p.aw4[b * 256 + tid];
    __syncthreads();
    const float* Xb = X3 + (size_t)b * SS * VEC;
    float acc = 0.0f;
#pragma unroll 8
    for (int j = 0; j < 256; ++j)
      acc = fmaf(sm.aws[j], Xb[(size_t)j * VEC + c], acc);
    acc += Xb[(size_t)lp * VEC + c];
    p.A4[b * VEC + c] = acc;
    __syncthreads();  // guard sm.aws for any further iteration
  }
  grid.sync();

  // ---- lnhead: LN(A4[b]) + 1280->32(relu)->12(relu)->2. 4 vblocks. ----
  for (int vb = blk; vb < BB; vb += G) {
    const int b = vb;
    float v[5];
    float sum = 0.0f;
#pragma unroll
    for (int k = 0; k < 5; ++k) {
      v[k] = p.A4[b * VEC + tid + k * 256];
      sum += v[k];
    }
    sum = blockSum(sum, red);
    const float m = sum * (1.0f / VEC);
    float sq = 0.0f;
#pragma unroll
    for (int k = 0; k < 5; ++k) {
      const float dl = v[k] - m;
      sq += dl * dl;
    }
    sq = blockSum(sq, red);
    const float rstd = rsqrtf(sq * (1.0f / VEC) + 1e-5f);
#pragma unroll
    for (int k = 0; k < 5; ++k) sm.t.xrow[tid + k * 256] = (v[k] - m) * rstd;
    __syncthreads();
    {
      const int n = tid & 31, sl = tid >> 5;
      float pp = 0.0f;
      for (int k = sl * 160; k < sl * 160 + 160; ++k)
        pp = fmaf(sm.t.xrow[k], p.hW1[(size_t)k * 32 + n], pp);
      sm.t.partial[tid] = pp;
    }
    __syncthreads();
    if (tid < 32) {
      float t = 0.0f;
#pragma unroll
      for (int s2 = 0; s2 < 8; ++s2) t += sm.t.partial[s2 * 32 + tid];
      sm.t.h1s[tid] = fmaxf(t + p.hb1[tid], 0.0f);
    }
    __syncthreads();
    if (tid < 12) {
      float t = 0.0f;
#pragma unroll
      for (int k = 0; k < 32; ++k) t = fmaf(sm.t.h1s[k], p.hW2[k * 12 + tid], t);
      sm.t.h2s[tid] = fmaxf(t + p.hb2[tid], 0.0f);
    }
    __syncthreads();
    if (tid < 2) {
      float t = 0.0f;
#pragma unroll
      for (int k = 0; k < 12; ++k) t = fmaf(sm.t.h2s[k], p.hW3[k * 2 + tid], t);
      p.out[b * 2 + tid] = t + p.hb3[tid];
    }
  }
}

// ---------------------------------------------------------------------------
extern "C" void kernel_launch(void* const* d_in, const int* in_sizes, int n_in,
                              void* d_out, int out_size, void* d_ws, size_t ws_size,
                              hipStream_t stream) {
  Params p;
  p.X = (const float*)d_in[0];
  p.lys = (const int*)d_in[1];
  for (int i = 0; i < 4; ++i) {
    p.Wq[i] = (const float*)d_in[2 + 3 * i];
    p.Wk[i] = (const float*)d_in[3 + 3 * i];
    p.wv[i] = (const float*)d_in[4 + 3 * i];
  }
  for (int i = 0; i < 3; ++i) {
    p.rW1[i] = (const float*)d_in[14 + 4 * i];
    p.rb1[i] = (const float*)d_in[15 + 4 * i];
    p.rW2[i] = (const float*)d_in[16 + 4 * i];
    p.rb2[i] = (const float*)d_in[17 + 4 * i];
  }
  p.hW1 = (const float*)d_in[26];
  p.hb1 = (const float*)d_in[27];
  p.hW2 = (const float*)d_in[28];
  p.hb2 = (const float*)d_in[29];
  p.hW3 = (const float*)d_in[30];
  p.hb3 = (const float*)d_in[31];
  p.out = (float*)d_out;

  float* ws = (float*)d_ws;
  p.QKp  = ws;                          // NPART x 262144
  p.Qd   = p.QKp + (long)NPART * QK_PS; // 1024*128
  p.KT   = p.Qd + 131072;               // 4*128*256
  p.attn = p.KT + 131072;               // 1024*256
  p.Yraw = p.attn + 262144;             // 1024*1280
  p.Yb   = p.Yraw + 1310720;            // 1024*1280
  p.Hp   = p.Yb + 1310720;              // NPART x 131072
  p.buf0 = p.Hp + (long)NPART * H_PS;   // 1024*1280
  p.buf1 = p.buf0 + 1310720;            // 1024*1280
  p.q4d  = p.buf1 + 1310720;            // 4*128
  p.aw4  = p.q4d + 512;                 // 4*256
  p.A4   = p.aw4 + 1024;                // 4*1280

  void* args[] = {&p};
  hipLaunchCooperativeKernel((const void*)net_k, dim3(256), dim3(256), args, 0,
                             stream);
}

// Round 7
// 454.204 us; speedup vs baseline: 3.0670x; 3.0670x over previous
//
#include <hip/hip_runtime.h>

// AttentionBasedNN: 4-layer additive attention + residual FCs + head.
// VEC=1280, HID=128, B=4, S=256. fp32 (no fp32 MFMA on CDNA4 -> vector ALU).
//
// Round-7: back to R4 multi-kernel (best: 445us), minus 4 dispatches:
//  - LN folded away: PV epilogue accumulates per-row sum/sumsq (shuffle +
//    atomics) into stats; FC1 normalizes on A-load; FC2 normalizes on
//    residual-load. (stats zeroed inside qksum, which precedes PV.)
//  - tail: scores4 folded into pv4s (20 blocks recompute cheap softmax);
//    q4 GEMV folded into kt4sum dispatch. 22 dispatches total.

#define DEV __device__ __forceinline__

static constexpr int VEC = 1280;
static constexpr int HID = 128;
static constexpr int BB  = 4;
static constexpr int SS  = 256;
static constexpr int MROWS = BB * SS;   // 1024
static constexpr int NPART = 8;         // split-K partials (QK, FC1, K4)
static constexpr float INV_VEC = 1.0f / 1280.0f;

DEV float ftanh(float x) {
  float e = __expf(2.0f * x);
  return 1.0f - __fdividef(2.0f, e + 1.0f);
}

DEV float waveSum(float v) {
#pragma unroll
  for (int off = 32; off > 0; off >>= 1) v += __shfl_xor(v, off, 64);
  return v;
}
DEV float waveMax(float v) {
#pragma unroll
  for (int off = 32; off > 0; off >>= 1) v = fmaxf(v, __shfl_xor(v, off, 64));
  return v;
}
// blockDim.x == 256 (4 waves) everywhere these are used.
DEV float blockSum(float v, float* red) {
  v = waveSum(v);
  int tid = threadIdx.x;
  if ((tid & 63) == 0) red[tid >> 6] = v;
  __syncthreads();
  float r = (red[0] + red[1]) + (red[2] + red[3]);
  __syncthreads();
  return r;
}
DEV float blockMax(float v, float* red) {
  v = waveMax(v);
  int tid = threadIdx.x;
  if ((tid & 63) == 0) red[tid >> 6] = v;
  __syncthreads();
  float r = fmaxf(fmaxf(red[0], red[1]), fmaxf(red[2], red[3]));
  __syncthreads();
  return r;
}

// ---------------------------------------------------------------------------
// fp32 GEMM, 64x64 tile, BK=16, 256 threads, 4x4 microtile, register
// double-buffered staging.
// MODE 0 plain | 1 split-K (z: k-slice kChunk, C += z*sCb disjoint partials)
//        | 2 batched (z: A += z*sAb, B += z*sBb, C/res += z*sCb).
// AFUSE: A = relu(sum of NPART partials (stride aPart) + aBias[k]).
// ALN:   A = (A - mean[row]) * rstd[row] from stats (row = m0+ar, fixed/thread).
// OBIAS: += oBias[n].  RESP: += res[m][n].  RESLN: += LN(res[m][n]) via stats.
// STATS: epilogue accumulates per-row sum/sumsq -> atomicAdd into Ssum/Ssq
//        (global stats row = (MODE==2 ? z*SS : 0) + m).
// ---------------------------------------------------------------------------
template <int MODE, bool AFUSE, bool ALN, bool OBIAS, bool RESLN, bool RESP,
          bool STATS>
__global__ __launch_bounds__(256) void gemm_k(
    const float* __restrict__ A, long sAb, long aPart,
    const float* __restrict__ B0, const float* __restrict__ B1, int nSplitB,
    long sBb, int ldB,
    float* __restrict__ C, long sCb,
    const float* __restrict__ aBias, const float* __restrict__ oBias,
    const float* __restrict__ res,
    float* __restrict__ Ssum, float* __restrict__ Ssq,
    int N, int K, int kChunk) {
  const int n0 = blockIdx.x * 64;
  const int m0 = blockIdx.y * 64;
  const int z  = blockIdx.z;

  const float* Ab = A + (MODE == 2 ? (long)z * sAb : 0L);
  float*       Cb = C + (MODE >= 1 ? (long)z * sCb : 0L);
  const float* resb = (RESP || RESLN)
                          ? (res + (MODE == 2 ? (long)z * sCb : 0L))
                          : nullptr;
  const float* Bsel;
  int nb;
  if (n0 < nSplitB) { Bsel = B0; nb = n0; } else { Bsel = B1; nb = n0 - nSplitB; }
  if (MODE == 2) Bsel += (long)z * sBb;

  const int kBeg = (MODE == 1) ? z * kChunk : 0;
  const int kEnd = (MODE == 1) ? kBeg + kChunk : K;

  __shared__ float As[16][68];  // [k][m]
  __shared__ float Bs[16][68];  // [k][n]

  const int tid = threadIdx.x;
  const int tx = tid & 15, ty = tid >> 4;
  const int ar = tid >> 2, ac = (tid & 3) << 2;   // A: row 0..63, k {0,4,8,12}
  const int br = tid >> 4, bc = (tid & 15) << 2;  // B: k-row 0..15, col 0..60

  float aMean = 0.0f, aRstd = 1.0f;
  if (ALN) {
    const int rm = m0 + ar;
    const float s = Ssum[rm], q = Ssq[rm];
    aMean = s * INV_VEC;
    aRstd = rsqrtf(q * INV_VEC - aMean * aMean + 1e-5f);
  }

  auto loadA = [&](int kt) -> float4 {
    const size_t off = (size_t)(m0 + ar) * K + kt + ac;
    float4 s = *(const float4*)(Ab + off);
    if (AFUSE) {
#pragma unroll
      for (int p2 = 1; p2 < NPART; ++p2) {
        const float4 t2 = *(const float4*)(Ab + (long)p2 * aPart + off);
        s.x += t2.x; s.y += t2.y; s.z += t2.z; s.w += t2.w;
      }
      const float4 bz = *(const float4*)(aBias + kt + ac);
      s.x = fmaxf(s.x + bz.x, 0.0f);
      s.y = fmaxf(s.y + bz.y, 0.0f);
      s.z = fmaxf(s.z + bz.z, 0.0f);
      s.w = fmaxf(s.w + bz.w, 0.0f);
    }
    if (ALN) {
      s.x = (s.x - aMean) * aRstd;
      s.y = (s.y - aMean) * aRstd;
      s.z = (s.z - aMean) * aRstd;
      s.w = (s.w - aMean) * aRstd;
    }
    return s;
  };
  auto loadB = [&](int kt) -> float4 {
    return *(const float4*)(Bsel + (size_t)(kt + br) * ldB + nb + bc);
  };

  float acc[4][4] = {};
  float4 a4 = loadA(kBeg);
  float4 b4 = loadB(kBeg);

  for (int kt = kBeg; kt < kEnd; kt += 16) {
    __syncthreads();
    As[ac + 0][ar] = a4.x;
    As[ac + 1][ar] = a4.y;
    As[ac + 2][ar] = a4.z;
    As[ac + 3][ar] = a4.w;
    *(float4*)&Bs[br][bc] = b4;
    __syncthreads();
    if (kt + 16 < kEnd) {  // prefetch next tile under compute
      a4 = loadA(kt + 16);
      b4 = loadB(kt + 16);
    }
#pragma unroll
    for (int kk = 0; kk < 16; ++kk) {
      const float4 av = *(const float4*)&As[kk][ty << 2];
      const float4 bv = *(const float4*)&Bs[kk][tx << 2];
      const float a[4] = {av.x, av.y, av.z, av.w};
      const float b[4] = {bv.x, bv.y, bv.z, bv.w};
#pragma unroll
      for (int i = 0; i < 4; ++i)
#pragma unroll
        for (int j = 0; j < 4; ++j) acc[i][j] = fmaf(a[i], b[j], acc[i][j]);
    }
  }

  float rs[4], rq[4];
#pragma unroll
  for (int i = 0; i < 4; ++i) {
    const int m = m0 + (ty << 2) + i;
    float mean = 0.0f, rstd = 1.0f;
    if (RESLN) {
      const float s = Ssum[m], q = Ssq[m];
      mean = s * INV_VEC;
      rstd = rsqrtf(q * INV_VEC - mean * mean + 1e-5f);
    }
    if (STATS) { rs[i] = 0.0f; rq[i] = 0.0f; }
#pragma unroll
    for (int j = 0; j < 4; ++j) {
      const int n = n0 + (tx << 2) + j;
      float v = acc[i][j];
      if (OBIAS) v += oBias[n];
      if (RESP) v += resb[(size_t)m * N + n];
      if (RESLN) v += (resb[(size_t)m * N + n] - mean) * rstd;
      Cb[(size_t)m * N + n] = v;
      if (STATS) { rs[i] += v; rq[i] = fmaf(v, v, rq[i]); }
    }
  }
  if (STATS) {
#pragma unroll
    for (int i = 0; i < 4; ++i) {
      float s = rs[i], q = rq[i];
#pragma unroll
      for (int msk = 1; msk < 16; msk <<= 1) {
        s += __shfl_xor(s, msk, 64);
        q += __shfl_xor(q, msk, 64);
      }
      if ((tid & 15) == 0) {
        const int rowg = (MODE == 2 ? z * SS : 0) + m0 + (ty << 2) + i;
        atomicAdd(&Ssum[rowg], s);
        atomicAdd(&Ssq[rowg], q);
      }
    }
  }
}

// ---------------------------------------------------------------------------
// Reduce NPART QK partials [1024][256] (cols 0..127=Q, 128..255=K) into
// Qd[1024][128] + KT[b][h][j]; blocks 0..7 also zero the stats buffer
// (2048 floats) for this layer's PV accumulation.
// ---------------------------------------------------------------------------
__global__ __launch_bounds__(256) void qksum_k(const float* __restrict__ QKp,
                                               long ps,
                                               float* __restrict__ Qd,
                                               float* __restrict__ KT,
                                               float* __restrict__ stats) {
  const int r = blockIdx.x, tid = threadIdx.x;
  if (r < 8) stats[r * 256 + tid] = 0.0f;
  const int b = r >> 8, j = r & 255;
  const size_t off = (size_t)r * 256 + tid;
  float v = 0.0f;
#pragma unroll
  for (int p = 0; p < NPART; ++p) v += QKp[(long)p * ps + off];
  if (tid < 128) {
    Qd[(size_t)r * 128 + tid] = v;
  } else {
    KT[(size_t)b * 32768 + (size_t)(tid - 128) * 256 + j] = v;
  }
}

// ---------------------------------------------------------------------------
// Scores + softmax, layers 1-3. Grid (128, B) = 512 blocks (2 q-rows each).
// Lane j reads KT[b][h][j] -> coalesced.
// ---------------------------------------------------------------------------
__global__ __launch_bounds__(256) void scores2_k(const float* __restrict__ Qd,
                                                 const float* __restrict__ KT,
                                                 const float* __restrict__ wv,
                                                 float* __restrict__ attn) {
  const int b = blockIdx.y, i0 = blockIdx.x * 2, tid = threadIdx.x;
  __shared__ float qs[2][128], wvs[128], red[4];
  {
    const int rr = tid >> 7, h = tid & 127;
    qs[rr][h] = Qd[(size_t)(b * 256 + i0 + rr) * 128 + h];
  }
  if (tid < 128) wvs[tid] = wv[tid];
  __syncthreads();

  const float* KTb = KT + (size_t)b * 32768 + tid;
  float s0 = 0.0f, s1 = 0.0f;
#pragma unroll 4
  for (int h = 0; h < 128; h += 4) {
    const float k0 = KTb[(h + 0) * 256];
    const float k1 = KTb[(h + 1) * 256];
    const float k2 = KTb[(h + 2) * 256];
    const float k3 = KTb[(h + 3) * 256];
    const float w0 = wvs[h], w1 = wvs[h + 1], w2 = wvs[h + 2], w3 = wvs[h + 3];
    s0 += w0 * ftanh(qs[0][h] + k0) + w1 * ftanh(qs[0][h + 1] + k1) +
          w2 * ftanh(qs[0][h + 2] + k2) + w3 * ftanh(qs[0][h + 3] + k3);
    s1 += w0 * ftanh(qs[1][h] + k0) + w1 * ftanh(qs[1][h + 1] + k1) +
          w2 * ftanh(qs[1][h + 2] + k2) + w3 * ftanh(qs[1][h + 3] + k3);
  }
  {
    const float mx = blockMax(s0, red);
    const float e = __expf(s0 - mx);
    const float tot = blockSum(e, red);
    attn[(size_t)(b * 256 + i0) * 256 + tid] = e / tot;
  }
  {
    const float mx = blockMax(s1, red);
    const float e = __expf(s1 - mx);
    const float tot = blockSum(e, red);
    attn[(size_t)(b * 256 + i0 + 1) * 256 + tid] = e / tot;
  }
}

// ---------------------------------------------------------------------------
// Tail: kt4sum (blocks 0..511, 2 rows each) + q4 GEMV (blocks 512..515).
// ---------------------------------------------------------------------------
__global__ __launch_bounds__(256) void kt4q4_k(const float* __restrict__ K4p,
                                               const float* __restrict__ X3,
                                               const float* __restrict__ Wq4,
                                               const int* __restrict__ lys,
                                               float* __restrict__ KT,
                                               float* __restrict__ q4d) {
  __shared__ float partial[256];
  const int vb = blockIdx.x, tid = threadIdx.x;
  if (vb < 512) {
    const int r = vb * 2 + (tid >> 7), h = tid & 127;
    const int b = r >> 8, j = r & 255;
    const size_t off = (size_t)r * 128 + h;
    float v = 0.0f;
#pragma unroll
    for (int p = 0; p < NPART; ++p) v += K4p[(long)p * 131072 + off];
    KT[(size_t)b * 32768 + (size_t)h * 256 + j] = v;
  } else {
    const int b = vb - 512;
    const int lp = lys[0];
    const float* xr = X3 + (size_t)(b * 256 + lp) * VEC;
    const int h = tid & 127, half = tid >> 7;
    float acc = 0.0f;
    const int k0 = half * 640;
    for (int k = k0; k < k0 + 640; ++k)
      acc = fmaf(xr[k], Wq4[(size_t)k * HID + h], acc);
    partial[tid] = acc;
    __syncthreads();
    if (tid < 128) q4d[b * 128 + tid] = partial[tid] + partial[tid + 128];
  }
}

// ---------------------------------------------------------------------------
// Tail: scores4 (recomputed per block, cheap) + PV slice + residual.
// Grid 20: b = blk&3, col-chunk cs = blk>>2.
// ---------------------------------------------------------------------------
__global__ __launch_bounds__(256) void pv4s_k(const float* __restrict__ q4d,
                                              const float* __restrict__ KT,
                                              const float* __restrict__ wv4,
                                              const int* __restrict__ lys,
                                              const float* __restrict__ X3,
                                              float* __restrict__ A4) {
  const int b = blockIdx.x & 3, cs = blockIdx.x >> 2, tid = threadIdx.x;
  __shared__ float qs[128], wvs[128], aw[256], red[4];
  const int lp = lys[0];
  if (tid < 128) {
    qs[tid] = q4d[b * 128 + tid];
    wvs[tid] = wv4[tid];
  }
  __syncthreads();
  const float* KTb = KT + (size_t)b * 32768 + tid;
  float s = 0.0f;
#pragma unroll 4
  for (int h = 0; h < 128; h += 4) {
    s += wvs[h + 0] * ftanh(qs[h + 0] + KTb[(h + 0) * 256]);
    s += wvs[h + 1] * ftanh(qs[h + 1] + KTb[(h + 1) * 256]);
    s += wvs[h + 2] * ftanh(qs[h + 2] + KTb[(h + 2) * 256]);
    s += wvs[h + 3] * ftanh(qs[h + 3] + KTb[(h + 3) * 256]);
  }
  const float mx = blockMax(s, red);
  const float e = __expf(s - mx);
  const float tot = blockSum(e, red);
  aw[tid] = e / tot;
  __syncthreads();

  const int c = cs * 256 + tid;
  const float* Xb = X3 + (size_t)b * SS * VEC;
  float acc = 0.0f;
#pragma unroll 8
  for (int j = 0; j < 256; ++j) acc = fmaf(aw[j], Xb[(size_t)j * VEC + c], acc);
  acc += Xb[(size_t)lp * VEC + c];
  A4[b * VEC + c] = acc;
}

// lnhead: grid (B). LN(A4[b]) then 1280->32(relu)->12(relu)->2 head.
__global__ __launch_bounds__(256) void lnhead_k(
    const float* __restrict__ A4,
    const float* __restrict__ hW1, const float* __restrict__ hb1,
    const float* __restrict__ hW2, const float* __restrict__ hb2,
    const float* __restrict__ hW3, const float* __restrict__ hb3,
    float* __restrict__ out) {
  const int b = blockIdx.x, tid = threadIdx.x;
  __shared__ float xrow[1280], partial[256], red[4];
  __shared__ float h1s[32], h2s[12];
  float v[5];
  float sum = 0.0f;
#pragma unroll
  for (int k = 0; k < 5; ++k) {
    v[k] = A4[b * VEC + tid + k * 256];
    sum += v[k];
  }
  sum = blockSum(sum, red);
  const float m = sum * INV_VEC;
  float sq = 0.0f;
#pragma unroll
  for (int k = 0; k < 5; ++k) {
    const float dl = v[k] - m;
    sq += dl * dl;
  }
  sq = blockSum(sq, red);
  const float rstd = rsqrtf(sq * INV_VEC + 1e-5f);
#pragma unroll
  for (int k = 0; k < 5; ++k) xrow[tid + k * 256] = (v[k] - m) * rstd;
  __syncthreads();
  {
    const int n = tid & 31, sl = tid >> 5;
    float p = 0.0f;
    for (int k = sl * 160; k < sl * 160 + 160; ++k)
      p = fmaf(xrow[k], hW1[(size_t)k * 32 + n], p);
    partial[tid] = p;
  }
  __syncthreads();
  if (tid < 32) {
    float t = 0.0f;
#pragma unroll
    for (int s2 = 0; s2 < 8; ++s2) t += partial[s2 * 32 + tid];
    h1s[tid] = fmaxf(t + hb1[tid], 0.0f);
  }
  __syncthreads();
  if (tid < 12) {
    float t = 0.0f;
#pragma unroll
    for (int k = 0; k < 32; ++k) t = fmaf(h1s[k], hW2[k * 12 + tid], t);
    h2s[tid] = fmaxf(t + hb2[tid], 0.0f);
  }
  __syncthreads();
  if (tid < 2) {
    float t = 0.0f;
#pragma unroll
    for (int k = 0; k < 12; ++k) t = fmaf(h2s[k], hW3[k * 2 + tid], t);
    out[b * 2 + tid] = t + hb3[tid];
  }
}

// ---------------------------------------------------------------------------
extern "C" void kernel_launch(void* const* d_in, const int* in_sizes, int n_in,
                              void* d_out, int out_size, void* d_ws, size_t ws_size,
                              hipStream_t stream) {
  const float* X = (const float*)d_in[0];
  const int* lys = (const int*)d_in[1];
  const float* Wq[4] = {(const float*)d_in[2], (const float*)d_in[5],
                        (const float*)d_in[8], (const float*)d_in[11]};
  const float* Wk[4] = {(const float*)d_in[3], (const float*)d_in[6],
                        (const float*)d_in[9], (const float*)d_in[12]};
  const float* wv[4] = {(const float*)d_in[4], (const float*)d_in[7],
                        (const float*)d_in[10], (const float*)d_in[13]};
  const float* rW1[3] = {(const float*)d_in[14], (const float*)d_in[18],
                         (const float*)d_in[22]};
  const float* rb1[3] = {(const float*)d_in[15], (const float*)d_in[19],
                         (const float*)d_in[23]};
  const float* rW2[3] = {(const float*)d_in[16], (const float*)d_in[20],
                         (const float*)d_in[24]};
  const float* rb2[3] = {(const float*)d_in[17], (const float*)d_in[21],
                         (const float*)d_in[25]};
  const float* hW1 = (const float*)d_in[26];
  const float* hb1 = (const float*)d_in[27];
  const float* hW2 = (const float*)d_in[28];
  const float* hb2 = (const float*)d_in[29];
  const float* hW3 = (const float*)d_in[30];
  const float* hb3 = (const float*)d_in[31];
  float* out = (float*)d_out;

  // Workspace (floats), ~30 MB.
  float* ws = (float*)d_ws;
  const long QK_PS = 262144;                 // QK partial stride (1024*256)
  const long H_PS  = 131072;                 // FC1/K4 partial stride (1024*128)
  float* QKp   = ws;                         // NPART x 262144 (K4p reuses)
  float* Qd    = QKp + (long)NPART * QK_PS;  // 1024*128
  float* KT    = Qd + 131072;                // 4*128*256
  float* attn  = KT + 131072;                // 1024*256
  float* Yraw  = attn + 262144;              // 1024*1280
  float* Hp    = Yraw + 1310720;             // NPART x 131072
  float* buf0  = Hp + (long)NPART * H_PS;    // 1024*1280
  float* buf1  = buf0 + 1310720;             // 1024*1280
  float* stats = buf1 + 1310720;             // 2048 (sum[1024], sumsq[1024])
  float* q4d   = stats + 2048;               // 4*128
  float* A4    = q4d + 512;                  // 4*1280
  float* Ssum = stats, *Ssq = stats + 1024;

  const int NSPLIT_NONE = 1 << 30;
  const float* P[3] = {X, buf0, buf1};
  float* Q[3] = {buf0, buf1, buf0};

  for (int l = 0; l < 3; ++l) {
    const float* Xin = P[l];
    // QKp[z] = Xin @ [Wq|Wk] over K-slice z. 512 blocks.
    gemm_k<1, false, false, false, false, false, false>
        <<<dim3(4, 16, NPART), 256, 0, stream>>>(
            Xin, 0, 0, Wq[l], Wk[l], HID, 0, HID, QKp, QK_PS, nullptr, nullptr,
            nullptr, nullptr, nullptr, 256, VEC, 160);
    // Reduce partials -> Qd + KT; zero stats. 1024 blocks.
    qksum_k<<<dim3(MROWS), 256, 0, stream>>>(QKp, QK_PS, Qd, KT, stats);
    // attn = softmax(wv . tanh(q_i + k_j)). 512 blocks.
    scores2_k<<<dim3(128, BB), 256, 0, stream>>>(Qd, KT, wv[l], attn);
    // Yraw = attn @ Xin + Xin (batched, residual fused) + row stats. 320 blocks.
    gemm_k<2, false, false, false, false, true, true>
        <<<dim3(20, 4, BB), 256, 0, stream>>>(
            attn, (long)SS * SS, 0, Xin, Xin, NSPLIT_NONE, (long)SS * VEC, VEC,
            Yraw, (long)SS * VEC, nullptr, nullptr, Xin, Ssum, Ssq,
            VEC, SS, 0);
    // Hp[z] = LN(Yraw) @ rW1 (LN folded into A-load). 256 blocks.
    gemm_k<1, false, true, false, false, false, false>
        <<<dim3(2, 16, NPART), 256, 0, stream>>>(
            Yraw, 0, 0, rW1[l], rW1[l], NSPLIT_NONE, 0, HID, Hp, H_PS, nullptr,
            nullptr, nullptr, Ssum, Ssq, HID, VEC, 160);
    // Xout = relu(sum(Hp)+b1) @ rW2 + b2 + LN(Yraw). 320 blocks.
    gemm_k<0, true, false, true, true, false, false>
        <<<dim3(20, 16, 1), 256, 0, stream>>>(
            Hp, 0, H_PS, rW2[l], rW2[l], NSPLIT_NONE, 0, VEC, Q[l], 0, rb1[l],
            rb2[l], Yraw, Ssum, Ssq, VEC, HID, 0);
  }

  const float* X3 = Q[2];  // buf0
  // Layer 4: K-proj split-K (partials into QKp region). 256 blocks.
  gemm_k<1, false, false, false, false, false, false>
      <<<dim3(2, 16, NPART), 256, 0, stream>>>(
          X3, 0, 0, Wk[3], Wk[3], NSPLIT_NONE, 0, HID, QKp, H_PS, nullptr,
          nullptr, nullptr, nullptr, nullptr, HID, VEC, 160);
  // kt4sum + q4 GEMV. 516 blocks.
  kt4q4_k<<<dim3(516), 256, 0, stream>>>(QKp, X3, Wq[3], lys, KT, q4d);
  // scores4 (recomputed) + PV slice + residual. 20 blocks.
  pv4s_k<<<dim3(20), 256, 0, stream>>>(q4d, KT, wv[3], lys, X3, A4);
  // LN + head. 4 blocks.
  lnhead_k<<<dim3(BB), 256, 0, stream>>>(A4, hW1, hb1, hW2, hb2, hW3, hb3, out);
}